// Round 8
// baseline (76.609 us; speedup 1.0000x reference)
//
#include <hip/hip_runtime.h>
#include <hip/hip_bf16.h>
#include <math.h>

namespace {
constexpr int Bn = 4, Cn = 64, Hn = 240, Wn = 320;
constexpr int HW = Hn * Wn;
constexpr int Npix = Bn * HW;
constexpr float EPS = 1e-5f;
constexpr float SLOPE = 0.2f;
constexpr int TM = 16, TN = 16;              // output tile
constexpr int HR = TM + 2, HC = TN + 2;      // halo 18 x 18
constexpr int NPXT = HR * HC;                // 324 pixels
constexpr int NGR = NPXT * 4;                // 1296 granules (16B) per phase
constexpr int PHB = 1344 * 16;               // 21504 B (pad for gll tail)
constexpr int WROWS = 31, WCOLS = 31;        // depth sample window
constexpr size_t BMAT_BYTES = 4 * 9 * 2 * 64 * 8 * 2;    // 73728 (frag-major)
constexpr size_t CONST_BYTES = 1024;                      // dfA/dfB/eInv/eBias
constexpr size_t PLANE_BYTES = (size_t)Bn * HW * 32 * 2; // 19.66 MB per plane
constexpr size_t LO_OFF = BMAT_BYTES + CONST_BYTES;
constexpr size_t HI_OFF = LO_OFF + PLANE_BYTES;
constexpr size_t WS_NEED = HI_OFF + PLANE_BYTES;
}

typedef __attribute__((ext_vector_type(8))) short bf16x8;
typedef __attribute__((ext_vector_type(4))) float f32x4;

__device__ inline unsigned cvtpk(float lo, float hi) {
    unsigned r;
    asm("v_cvt_pk_bf16_f32 %0, %1, %2" : "=v"(r) : "v"(lo), "v"(hi));
    return r;
}

__device__ inline float fastexp(float x) {
    float e;
    asm("v_exp_f32 %0, %1" : "=v"(e) : "v"(x * 1.44269504f));
    return e;
}

__device__ inline float fastrcp(float x) {
    float r;
    asm("v_rcp_f32 %0, %1" : "=v"(r) : "v"(x));
    return r;
}

__device__ inline unsigned short f2bf(float f) {
    unsigned u = __builtin_bit_cast(unsigned, f);
    return (unsigned short)((u + 0x7fffu + ((u >> 16) & 1u)) >> 16);
}

// ---- pre-pass 1: weights -> bf16 fragment-major Bf[p][t][n][lane64][8]
//      + (block 18) constant LUT: dfA[64] dfB[64] eInv[27] eBias[27] ----
__global__ __launch_bounds__(256) void prep_B(
    const float* __restrict__ ww, const float* __restrict__ wo,
    const float* __restrict__ w1, const float* __restrict__ g1,
    const float* __restrict__ b1, const float* __restrict__ m1,
    const float* __restrict__ v1,
    const float* __restrict__ gw, const float* __restrict__ bw,
    const float* __restrict__ mw, const float* __restrict__ vw,
    const float* __restrict__ go, const float* __restrict__ bo,
    const float* __restrict__ mo, const float* __restrict__ vo,
    unsigned short* __restrict__ Bf, float* __restrict__ cst)
{
    if (blockIdx.x == 18) {
        const int i = threadIdx.x;
        if (i < 64) {
            const float inv = g1[i] * rsqrtf(v1[i] + EPS);
            cst[i] = w1[i] * inv;              // dfA
            cst[64 + i] = b1[i] - m1[i] * inv; // dfB
        } else if (i < 64 + 27) {
            const int j = i - 64;
            float g, bb, m, v;
            if (j < 9) { g = gw[j]; bb = bw[j]; m = mw[j]; v = vw[j]; }
            else       { g = go[j - 9]; bb = bo[j - 9]; m = mo[j - 9]; v = vo[j - 9]; }
            const float inv = g * rsqrtf(v + EPS);
            cst[128 + j] = inv;                 // eInv
            cst[155 + j] = bb - m * inv;        // eBias
        }
        return;
    }
    const int f = blockIdx.x * 256 + threadIdx.x;   // frag id over 4608
    if (f >= 4608) return;
    const int lane = f & 63, rest = f >> 6;
    const int n = rest & 1, tp = rest >> 1;         // tp = p*9 + t
    const int t = tp % 9, p = tp / 9;
    const int col = n * 16 + (lane & 15);
    const int hi = lane >> 4;
    unsigned short o[8];
    #pragma unroll
    for (int j = 0; j < 8; ++j) {
        const int c = p * 32 + hi * 8 + j;
        float v = 0.0f;
        if (col < 9)       v = ww[((size_t)col * 128 + c) * 9 + t];
        else if (col < 27) v = wo[((size_t)(col - 9) * 128 + c) * 9 + t];
        o[j] = f2bf(v);
    }
    uint4 u;
    u.x = (unsigned)o[0] | ((unsigned)o[1] << 16);
    u.y = (unsigned)o[2] | ((unsigned)o[3] << 16);
    u.z = (unsigned)o[4] | ((unsigned)o[5] << 16);
    u.w = (unsigned)o[6] | ((unsigned)o[7] << 16);
    *(uint4*)(Bf + (size_t)f * 8) = u;
}

// ---- pre-pass 2: feature f32 -> bf16 pixel-major planes (pre-swizzled) ----
__global__ __launch_bounds__(512) void prep_F(
    const float* __restrict__ feature,
    unsigned short* __restrict__ lo, unsigned short* __restrict__ hi)
{
    const int y = blockIdx.x;            // 0..239
    const int b = blockIdx.y;
    const int lane = threadIdx.x & 63;
    const int g = threadIdx.x >> 6;      // 0..7
    const int c0 = g * 8;
    unsigned short* __restrict__ plane = (g < 4) ? lo : hi;
    const int slotg = g & 3;
    const float* __restrict__ fb = feature + (size_t)b * Cn * HW + (size_t)y * Wn;
    #pragma unroll
    for (int s = 0; s < 5; ++s) {
        const int x = s * 64 + lane;
        float v[8];
        #pragma unroll
        for (int j = 0; j < 8; ++j)
            v[j] = fb[(size_t)(c0 + j) * HW + x];
        uint4 u;
        u.x = cvtpk(v[0], v[1]); u.y = cvtpk(v[2], v[3]);
        u.z = cvtpk(v[4], v[5]); u.w = cvtpk(v[6], v[7]);
        const int slot = (slotg + ((x + 1) >> 1)) & 3;
        *(uint4*)(plane + (size_t)(b * HW + y * Wn + x) * 32 + slot * 8) = u;
    }
}

// ---- main: 3-barrier pipeline; df phases computed in registers ----------
__global__ __launch_bounds__(256, 3) void dkn_main(
    const unsigned short* __restrict__ Bf,
    const float* __restrict__ cst,
    const unsigned short* __restrict__ catLo,
    const unsigned short* __restrict__ catHi,
    const float* __restrict__ depth,
    float* __restrict__ out)
{
    __shared__ __align__(16) char lds[2 * PHB + 3968];   // 46976 B -> 3 blocks/CU

    const int tid = threadIdx.x;
    const int lane = tid & 63, wv = tid >> 6;     // 4 waves
    const int l15 = lane & 15, hi16 = lane >> 4;
    const int b = blockIdx.z;
    const int h0 = blockIdx.y * TM;
    const int w0 = blockIdx.x * TN;
    const float* __restrict__ dimg = depth + (size_t)b * HW;
    const float* __restrict__ dfA = cst;
    const float* __restrict__ dfB = cst + 64;
    const float* __restrict__ eInv = cst + 128;
    const float* __restrict__ eBias = cst + 155;

    char* buf0 = lds;
    char* buf1 = lds + PHB;
    float* winp = (float*)(lds + 2 * PHB);        // 31*31*4 B, dedicated
    float* ldsT = (float*)lds;                    // aliases bufs, post-GEMM

    const bool interior = (blockIdx.y >= 1) && (blockIdx.y <= 13)
                       && (blockIdx.x >= 1) && (blockIdx.x <= 18);

    // ---- early register loads: depth window, df A-operands, df consts ----
    float wvv[4];
    int widx[4];
    bool wok[4];
    #pragma unroll
    for (int s = 0; s < 4; ++s) {
        const int i = s * 256 + tid;              // over 961
        const int r = (i * 2115) >> 16;           // i/31, exact for i<=960
        const int c = i - r * 31;
        const int y = h0 + r - 7, x = w0 + c - 7;
        const bool inw = (i < WROWS * WCOLS);
        const bool oki = inw && ((unsigned)y < (unsigned)Hn) && ((unsigned)x < (unsigned)Wn);
        widx[s] = i;
        wok[s] = inw;
        wvv[s] = oki ? dimg[y * Wn + x] : 0.0f;
    }

    const int r0 = 4 * wv;
    float dreg[6][3], oky6[6], okx3[3];
    #pragma unroll
    for (int dx = 0; dx < 3; ++dx) {
        const int x = w0 + l15 + dx - 1;
        okx3[dx] = ((unsigned)x < (unsigned)Wn) ? 1.0f : 0.0f;
    }
    #pragma unroll
    for (int i = 0; i < 6; ++i) {
        const int y = h0 + r0 + i - 1;
        oky6[i] = ((unsigned)y < (unsigned)Hn) ? 1.0f : 0.0f;
        const int yc = min(max(y, 0), Hn - 1);
        #pragma unroll
        for (int dx = 0; dx < 3; ++dx) {
            const int x = w0 + l15 + dx - 1;
            const int xc = min(max(x, 0), Wn - 1);
            dreg[i][dx] = dimg[yc * Wn + xc];
        }
    }

    float A8[2][8], B8[2][8];
    #pragma unroll
    for (int p = 0; p < 2; ++p)
        #pragma unroll
        for (int j = 0; j < 8; ++j) {
            A8[p][j] = dfA[p * 32 + hi16 * 8 + j];
            B8[p][j] = dfB[p * 32 + hi16 * 8 + j];
        }

    // ---- issue BOTH feature gll batches (after reg loads, so df-use waits
    //      are counted and don't drain the gll queue) ----
    auto issue_gll = [&](const unsigned short* __restrict__ plane, char* buf) {
        #pragma unroll
        for (int s = 0; s < 6; ++s) {
            const int base = s * 256 + wv * 64;    // wave-uniform
            if (base < NGR) {
                int i = base + lane;
                i = min(i, NGR - 1);               // tail lanes duplicate (into pad)
                const int px = i >> 2, slot = i & 3;
                const int r = (px * 57) >> 10;
                const int lc = px - r * 18;
                const int y = min(max(h0 + r - 1, 0), Hn - 1);
                const int x = min(max(w0 + lc - 1, 0), Wn - 1);
                const unsigned short* src =
                    plane + (size_t)(b * HW + y * Wn + x) * 32 + slot * 8;
                __builtin_amdgcn_global_load_lds(
                    (const __attribute__((address_space(1))) void*)src,
                    (__attribute__((address_space(3))) void*)(buf + (size_t)base * 16),
                    16, 0, 0);
            }
        }
    };
    issue_gll(catLo, buf0);
    issue_gll(catHi, buf1);

    auto borderfix = [&](char* buf) {
        #pragma unroll
        for (int s = 0; s < 6; ++s) {
            const int i = s * 256 + tid;
            if (i < NGR) {
                const int px = i >> 2;
                const int r = (px * 57) >> 10;
                const int lc = px - r * 18;
                const int y = h0 + r - 1, x = w0 + lc - 1;
                if (((unsigned)y >= (unsigned)Hn) || ((unsigned)x >= (unsigned)Wn)) {
                    uint4 z = {0u, 0u, 0u, 0u};
                    *(uint4*)(buf + (size_t)i * 16) = z;
                }
            }
        }
    };

    // ---- MFMA machinery ----
    f32x4 acc[4][2] = {};

    auto do_dy = [&](const bf16x8* Aq0, const bf16x8* Aq1,
                     const bf16x8* Aq2, const bf16x8* Aq3, const bf16x8* bb) {
        #pragma unroll
        for (int dx = 0; dx < 3; ++dx) {
            acc[0][0] = __builtin_amdgcn_mfma_f32_16x16x32_bf16(Aq0[dx], bb[dx*2+0], acc[0][0], 0, 0, 0);
            acc[0][1] = __builtin_amdgcn_mfma_f32_16x16x32_bf16(Aq0[dx], bb[dx*2+1], acc[0][1], 0, 0, 0);
            acc[1][0] = __builtin_amdgcn_mfma_f32_16x16x32_bf16(Aq1[dx], bb[dx*2+0], acc[1][0], 0, 0, 0);
            acc[1][1] = __builtin_amdgcn_mfma_f32_16x16x32_bf16(Aq1[dx], bb[dx*2+1], acc[1][1], 0, 0, 0);
            acc[2][0] = __builtin_amdgcn_mfma_f32_16x16x32_bf16(Aq2[dx], bb[dx*2+0], acc[2][0], 0, 0, 0);
            acc[2][1] = __builtin_amdgcn_mfma_f32_16x16x32_bf16(Aq2[dx], bb[dx*2+1], acc[2][1], 0, 0, 0);
            acc[3][0] = __builtin_amdgcn_mfma_f32_16x16x32_bf16(Aq3[dx], bb[dx*2+0], acc[3][0], 0, 0, 0);
            acc[3][1] = __builtin_amdgcn_mfma_f32_16x16x32_bf16(Aq3[dx], bb[dx*2+1], acc[3][1], 0, 0, 0);
        }
    };

    // df phase: A-frags computed in registers (identical math to staged path)
    auto mfma_df = [&](int p) {
        const unsigned short* Bp = Bf + (size_t)p * 9216;
        auto ldb = [&](int idx) -> bf16x8 {
            return *(const bf16x8*)(Bp + ((size_t)idx * 64 + lane) * 8);
        };
        auto mk = [&](int i, int dx) -> bf16x8 {
            const float dd = dreg[i][dx];
            const float okf = oky6[i] * okx3[dx];
            float vv[8];
            #pragma unroll
            for (int j = 0; j < 8; ++j) {
                float u = fmaf(A8[p][j], dd, B8[p][j]);
                u = fmaxf(u, SLOPE * u);
                vv[j] = u * okf;
            }
            union { uint4 q; bf16x8 v; } r;
            r.q.x = cvtpk(vv[0], vv[1]); r.q.y = cvtpk(vv[2], vv[3]);
            r.q.z = cvtpk(vv[4], vv[5]); r.q.w = cvtpk(vv[6], vv[7]);
            return r.v;
        };
        bf16x8 a0[3], a1[3], a2[3], a3[3], a4[3], a5[3];
        bf16x8 b0[6], b1[6], b2[6];
        #pragma unroll
        for (int dx = 0; dx < 3; ++dx) {
            a0[dx] = mk(0, dx); a1[dx] = mk(1, dx);
            a2[dx] = mk(2, dx); a3[dx] = mk(3, dx);
        }
        #pragma unroll
        for (int i = 0; i < 6; ++i) b0[i] = ldb(i);
        #pragma unroll
        for (int dx = 0; dx < 3; ++dx) a4[dx] = mk(4, dx);
        #pragma unroll
        for (int i = 0; i < 6; ++i) b1[i] = ldb(6 + i);
        do_dy(a0, a1, a2, a3, b0);
        #pragma unroll
        for (int dx = 0; dx < 3; ++dx) a5[dx] = mk(5, dx);
        #pragma unroll
        for (int i = 0; i < 6; ++i) b2[i] = ldb(12 + i);
        do_dy(a1, a2, a3, a4, b1);
        do_dy(a2, a3, a4, a5, b2);
    };

    // feature phase: A-frags from LDS (rolling window)
    auto mfma_feat = [&](int p, const char* buf) {
        const unsigned short* Bp = Bf + (size_t)p * 9216;
        auto lda = [&](int row, int dx) -> bf16x8 {
            const int col = l15 + dx;                       // 0..17
            const int slot = (hi16 + (col >> 1)) & 3;
            return *(const bf16x8*)(buf + (row * HC + col) * 64 + slot * 16);
        };
        auto ldb = [&](int idx) -> bf16x8 {
            return *(const bf16x8*)(Bp + ((size_t)idx * 64 + lane) * 8);
        };
        bf16x8 a0[3], a1[3], a2[3], a3[3], a4[3], a5[3];
        bf16x8 b0[6], b1[6], b2[6];
        #pragma unroll
        for (int dx = 0; dx < 3; ++dx) {
            a0[dx] = lda(r0 + 0, dx); a1[dx] = lda(r0 + 1, dx);
            a2[dx] = lda(r0 + 2, dx); a3[dx] = lda(r0 + 3, dx);
        }
        #pragma unroll
        for (int i = 0; i < 6; ++i) b0[i] = ldb(i);
        #pragma unroll
        for (int dx = 0; dx < 3; ++dx) a4[dx] = lda(r0 + 4, dx);
        #pragma unroll
        for (int i = 0; i < 6; ++i) b1[i] = ldb(6 + i);
        do_dy(a0, a1, a2, a3, b0);
        #pragma unroll
        for (int dx = 0; dx < 3; ++dx) a5[dx] = lda(r0 + 5, dx);
        #pragma unroll
        for (int i = 0; i < 6; ++i) b2[i] = ldb(12 + i);
        do_dy(a1, a2, a3, a4, b1);
        do_dy(a2, a3, a4, a5, b2);
    };

    // ---- df phases run while feature gll is in flight ----
    mfma_df(0);
    mfma_df(1);

    asm volatile("s_waitcnt vmcnt(0)" ::: "memory");
    #pragma unroll
    for (int s = 0; s < 4; ++s)
        if (wok[s]) winp[widx[s]] = wvv[s];
    if (!interior) { borderfix(buf0); borderfix(buf1); }
    __syncthreads();                               // barrier #1

    mfma_feat(2, buf0);
    mfma_feat(3, buf1);
    __syncthreads();                               // barrier #2

    // ---- transpose acc -> ldsT [256 px][33 f32] ----
    #pragma unroll
    for (int m = 0; m < 4; ++m) {
        const int oy = 4 * wv + m;
        #pragma unroll
        for (int n = 0; n < 2; ++n) {
            #pragma unroll
            for (int r = 0; r < 4; ++r) {
                const int ox = hi16 * 4 + r;
                ldsT[(oy * TN + ox) * 33 + n * 16 + l15] = acc[m][n][r];
            }
        }
    }
    __syncthreads();                               // barrier #3

    // ---- per-pixel epilogue ----
    {
        const int oyl = tid >> 4, oxl = tid & 15;
        const int h = h0 + oyl, w = w0 + oxl;
        const float* row = ldsT + (size_t)tid * 33;

        float wgt[9];
        float wsum = 0.0f;
        #pragma unroll
        for (int j = 0; j < 9; ++j) {
            const float x = fmaf(row[j], eInv[j], eBias[j]);
            const float e = fastexp(x);                 // e^x
            const float s = e * fastrcp(1.0f + e);      // sigmoid
            wgt[j] = s;
            wsum += s;
        }
        const float wm = wsum * (1.0f / 9.0f);
        #pragma unroll
        for (int j = 0; j < 9; ++j) wgt[j] -= wm;

        float offv[18];
        #pragma unroll
        for (int j = 0; j < 18; ++j)
            offv[j] = fmaf(row[9 + j], eInv[9 + j], eBias[9 + j]);

        auto sampleW = [&](float xf, float yf) -> float {
            const bool vld = (xf >= 0.0f) & (xf <= 14.0f) & (yf >= 0.0f) & (yf <= 14.0f);
            const int xi = min(max((int)xf, 0), 14);
            const int yi = min(max((int)yf, 0), 14);
            const float v = winp[(oyl + yi) * WCOLS + (oxl + xi)];
            return vld ? v : 0.0f;
        };

        float res = 0.0f;
        #pragma unroll
        for (int i = 0; i < 3; ++i) {
            #pragma unroll
            for (int j = 0; j < 3; ++j) {
                const int t = i * 3 + j;
                const float ox = offv[2 * t + 0];
                const float oy = offv[2 * t + 1];
                const float ix = (7.0f + (float)i + ox) * (14.0f / 15.0f);
                const float iy = (7.0f + (float)j + oy) * (14.0f / 15.0f);
                const float x0 = floorf(ix), y0 = floorf(iy);
                const float wx1 = ix - x0, wy1 = iy - y0;
                const float wx0 = 1.0f - wx1, wy0 = 1.0f - wy1;
                const float s =
                      sampleW(x0,        y0       ) * wx0 * wy0
                    + sampleW(x0 + 1.0f, y0       ) * wx1 * wy0
                    + sampleW(x0,        y0 + 1.0f) * wx0 * wy1
                    + sampleW(x0 + 1.0f, y0 + 1.0f) * wx1 * wy1;
                res = fmaf(s, wgt[t], res);
            }
        }
        out[((size_t)b * Hn + h) * Wn + w] = res + winp[(oyl + 7) * WCOLS + (oxl + 7)];
    }
}

// ---------------- round-1 fallback (fp32, fused, proven) ----------------
__global__ __launch_bounds__(256) void dkn_fused_f32(
    const float* __restrict__ depth, const float* __restrict__ feature,
    const float* __restrict__ w1, const float* __restrict__ g1,
    const float* __restrict__ b1, const float* __restrict__ m1,
    const float* __restrict__ v1, const float* __restrict__ ww,
    const float* __restrict__ gw, const float* __restrict__ bw,
    const float* __restrict__ mw, const float* __restrict__ vw,
    const float* __restrict__ wo, const float* __restrict__ go,
    const float* __restrict__ bo, const float* __restrict__ mo,
    const float* __restrict__ vo, float* __restrict__ out)
{
    const int n = blockIdx.x * blockDim.x + threadIdx.x;
    if (n >= Npix) return;
    const int w = n % Wn;
    const int h = (n / Wn) % Hn;
    const int b = n / (Wn * Hn);
    const float* __restrict__ dimg = depth + (size_t)b * HW;
    const float* __restrict__ fimg = feature + (size_t)b * Cn * HW;
    float d9[9], msk[9]; int off9[9];
    #pragma unroll
    for (int ky = 0; ky < 3; ++ky)
        #pragma unroll
        for (int kx = 0; kx < 3; ++kx) {
            const int t = ky * 3 + kx;
            const int y = h + ky - 1, x = w + kx - 1;
            const bool ok = ((unsigned)y < (unsigned)Hn) && ((unsigned)x < (unsigned)Wn);
            off9[t] = min(max(y, 0), Hn - 1) * Wn + min(max(x, 0), Wn - 1);
            d9[t] = dimg[off9[t]];
            msk[t] = ok ? 1.0f : 0.0f;
        }
    float accW[9], accO[18];
    #pragma unroll
    for (int o = 0; o < 9; ++o) accW[o] = 0.0f;
    #pragma unroll
    for (int o = 0; o < 18; ++o) accO[o] = 0.0f;
    for (int c = 0; c < Cn; ++c) {
        const float inv = g1[c] * rsqrtf(v1[c] + EPS);
        const float A = w1[c] * inv, Bc = b1[c] - m1[c] * inv;
        float v9[9];
        #pragma unroll
        for (int t = 0; t < 9; ++t) {
            const float x = fmaf(A, d9[t], Bc);
            v9[t] = msk[t] * fmaxf(x, SLOPE * x);
        }
        const float* wwc = ww + c * 9;
        const float* woc = wo + c * 9;
        #pragma unroll
        for (int o = 0; o < 9; ++o)
            #pragma unroll
            for (int t = 0; t < 9; ++t) accW[o] = fmaf(wwc[o * 1152 + t], v9[t], accW[o]);
        #pragma unroll
        for (int o = 0; o < 18; ++o)
            #pragma unroll
            for (int t = 0; t < 9; ++t) accO[o] = fmaf(woc[o * 1152 + t], v9[t], accO[o]);
    }
    for (int c = 0; c < Cn; ++c) {
        const float* fc = fimg + (size_t)c * HW;
        float v9[9];
        #pragma unroll
        for (int t = 0; t < 9; ++t) v9[t] = msk[t] * fc[off9[t]];
        const float* wwc = ww + (64 + c) * 9;
        const float* woc = wo + (64 + c) * 9;
        #pragma unroll
        for (int o = 0; o < 9; ++o)
            #pragma unroll
            for (int t = 0; t < 9; ++t) accW[o] = fmaf(wwc[o * 1152 + t], v9[t], accW[o]);
        #pragma unroll
        for (int o = 0; o < 18; ++o)
            #pragma unroll
            for (int t = 0; t < 9; ++t) accO[o] = fmaf(woc[o * 1152 + t], v9[t], accO[o]);
    }
    float wgt[9];
    float wsum = 0.0f;
    #pragma unroll
    for (int j = 0; j < 9; ++j) {
        const float inv = gw[j] * rsqrtf(vw[j] + EPS);
        const float x = fmaf(accW[j], inv, bw[j] - mw[j] * inv);
        const float s = 1.0f / (1.0f + expf(-x));
        wgt[j] = s; wsum += s;
    }
    const float wm = wsum * (1.0f / 9.0f);
    #pragma unroll
    for (int j = 0; j < 9; ++j) wgt[j] -= wm;
    float offv[18];
    #pragma unroll
    for (int j = 0; j < 18; ++j) {
        const float inv = go[j] * rsqrtf(vo[j] + EPS);
        offv[j] = fmaf(accO[j], inv, bo[j] - mo[j] * inv);
    }
    auto sampleD = [&](float xf, float yf) -> float {
        const bool vld = (xf >= 0.0f) & (xf <= 14.0f) & (yf >= 0.0f) & (yf <= 14.0f);
        const float xc = fminf(fmaxf(xf, 0.0f), 14.0f);
        const float yc = fminf(fmaxf(yf, 0.0f), 14.0f);
        const int xi = (int)xc, yi = (int)yc;
        const int yy = h + yi - 7, xx = w + xi - 7;
        const bool okimg = ((unsigned)yy < (unsigned)Hn) && ((unsigned)xx < (unsigned)Wn);
        return (vld && okimg) ? dimg[yy * Wn + xx] : 0.0f;
    };
    float res = 0.0f;
    #pragma unroll
    for (int i = 0; i < 3; ++i)
        #pragma unroll
        for (int j = 0; j < 3; ++j) {
            const int t = i * 3 + j;
            const float ox = offv[2 * t + 0], oy = offv[2 * t + 1];
            const float ix = (7.0f + (float)i + ox) * (14.0f / 15.0f);
            const float iy = (7.0f + (float)j + oy) * (14.0f / 15.0f);
            const float x0 = floorf(ix), y0 = floorf(iy);
            const float wx1 = ix - x0, wy1 = iy - y0;
            const float s = sampleD(x0, y0) * (1.0f - wx1) * (1.0f - wy1)
                          + sampleD(x0 + 1.0f, y0) * wx1 * (1.0f - wy1)
                          + sampleD(x0, y0 + 1.0f) * (1.0f - wx1) * wy1
                          + sampleD(x0 + 1.0f, y0 + 1.0f) * wx1 * wy1;
            res = fmaf(s, wgt[t], res);
        }
    out[n] = res + dimg[h * Wn + w];
}

extern "C" void kernel_launch(void* const* d_in, const int* in_sizes, int n_in,
                              void* d_out, int out_size, void* d_ws, size_t ws_size,
                              hipStream_t stream) {
    (void)in_sizes; (void)n_in; (void)out_size;
    const float* depth   = (const float*)d_in[0];
    const float* feature = (const float*)d_in[1];
    const float* w1 = (const float*)d_in[2];
    const float* g1 = (const float*)d_in[3];
    const float* b1 = (const float*)d_in[4];
    const float* m1 = (const float*)d_in[5];
    const float* v1 = (const float*)d_in[6];
    const float* ww = (const float*)d_in[7];
    const float* gw = (const float*)d_in[8];
    const float* bw = (const float*)d_in[9];
    const float* mw = (const float*)d_in[10];
    const float* vw = (const float*)d_in[11];
    const float* wo = (const float*)d_in[12];
    const float* go = (const float*)d_in[13];
    const float* bo = (const float*)d_in[14];
    const float* mo = (const float*)d_in[15];
    const float* vo = (const float*)d_in[16];
    float* out = (float*)d_out;

    if (ws_size >= WS_NEED) {
        unsigned short* Bmat  = (unsigned short*)d_ws;
        float* cst = (float*)((char*)d_ws + BMAT_BYTES);
        unsigned short* catLo = (unsigned short*)((char*)d_ws + LO_OFF);
        unsigned short* catHi = (unsigned short*)((char*)d_ws + HI_OFF);
        hipLaunchKernelGGL(prep_B, dim3(19), dim3(256), 0, stream,
                           ww, wo, w1, g1, b1, m1, v1,
                           gw, bw, mw, vw, go, bo, mo, vo, Bmat, cst);
        hipLaunchKernelGGL(prep_F, dim3(Hn, Bn), dim3(512), 0, stream,
                           feature, catLo, catHi);
        hipLaunchKernelGGL(dkn_main, dim3(Wn / TN, Hn / TM, Bn), dim3(256), 0, stream,
                           Bmat, cst, catLo, catHi, depth, out);
    } else {
        hipLaunchKernelGGL(dkn_fused_f32, dim3((Npix + 255) / 256), dim3(256), 0, stream,
                           depth, feature, w1, g1, b1, m1, v1,
                           ww, gw, bw, mw, vw, wo, go, bo, mo, vo, out);
    }
}

// Round 9
// 72.789 us; speedup vs baseline: 1.0525x; 1.0525x over previous
//
#include <hip/hip_runtime.h>
#include <hip/hip_bf16.h>
#include <math.h>

namespace {
constexpr int Bn = 4, Cn = 64, Hn = 240, Wn = 320;
constexpr int HW = Hn * Wn;
constexpr int Npix = Bn * HW;
constexpr float EPS = 1e-5f;
constexpr float SLOPE = 0.2f;
constexpr int TM = 16, TN = 16;              // output tile
constexpr int HR = TM + 2, HC = TN + 2;      // halo 18 x 18
constexpr int NPXT = HR * HC;                // 324 pixels
constexpr int NGR = NPXT * 4;                // 1296 granules (16B) per phase
constexpr int PHB = 1344 * 16;               // 21504 B (pad for gll tail)
constexpr int WROWS = 31, WCOLS = 31;        // depth sample window
constexpr int WINP_OFF = 27648;              // ldsT = 256*27*4 = 27648 B
constexpr int LDS_TOTAL = WINP_OFF + 3968;   // 31616 B -> 5 blocks/CU
constexpr size_t BMAT_BYTES = 4 * 9 * 2 * 64 * 8 * 2;    // 73728 (frag-major)
constexpr size_t CONST_BYTES = 1024;                      // dfA/dfB/eInv/eBias
constexpr size_t PLANE_BYTES = (size_t)Bn * HW * 32 * 2; // 19.66 MB per plane
constexpr size_t LO_OFF = BMAT_BYTES + CONST_BYTES;
constexpr size_t HI_OFF = LO_OFF + PLANE_BYTES;
constexpr size_t WS_NEED = HI_OFF + PLANE_BYTES;
}

typedef __attribute__((ext_vector_type(8))) short bf16x8;
typedef __attribute__((ext_vector_type(4))) float f32x4;

__device__ inline unsigned cvtpk(float lo, float hi) {
    unsigned r;
    asm("v_cvt_pk_bf16_f32 %0, %1, %2" : "=v"(r) : "v"(lo), "v"(hi));
    return r;
}

__device__ inline float fastexp(float x) {
    float e;
    asm("v_exp_f32 %0, %1" : "=v"(e) : "v"(x * 1.44269504f));
    return e;
}

__device__ inline float fastrcp(float x) {
    float r;
    asm("v_rcp_f32 %0, %1" : "=v"(r) : "v"(x));
    return r;
}

__device__ inline unsigned short f2bf(float f) {
    unsigned u = __builtin_bit_cast(unsigned, f);
    return (unsigned short)((u + 0x7fffu + ((u >> 16) & 1u)) >> 16);
}

// ---- merged pre-pass: feature f32 -> bf16 pixel-major planes (pre-swizzled)
//      + weight frags Bf[p][t][n][lane64][8] + constant LUT ----
__global__ __launch_bounds__(512) void prep_FB(
    const float* __restrict__ feature,
    const float* __restrict__ ww, const float* __restrict__ wo,
    const float* __restrict__ w1, const float* __restrict__ g1,
    const float* __restrict__ b1, const float* __restrict__ m1,
    const float* __restrict__ v1,
    const float* __restrict__ gw, const float* __restrict__ bw,
    const float* __restrict__ mw, const float* __restrict__ vw,
    const float* __restrict__ go, const float* __restrict__ bo,
    const float* __restrict__ mo, const float* __restrict__ vo,
    unsigned short* __restrict__ lo, unsigned short* __restrict__ hi,
    unsigned short* __restrict__ Bf, float* __restrict__ cst)
{
    const int tid = threadIdx.x;
    if (blockIdx.y == Bn) {
        const int bx = blockIdx.x;
        if (bx < 9) {
            // weight fragments: f over 4608 = 9 blocks x 512
            const int f = bx * 512 + tid;
            const int lane = f & 63, rest = f >> 6;
            const int n = rest & 1, tp = rest >> 1;   // tp = p*9 + t
            const int t = tp % 9, p = tp / 9;
            const int col = n * 16 + (lane & 15);
            const int hh = lane >> 4;
            unsigned short o[8];
            #pragma unroll
            for (int j = 0; j < 8; ++j) {
                const int c = p * 32 + hh * 8 + j;
                float v = 0.0f;
                if (col < 9)       v = ww[((size_t)col * 128 + c) * 9 + t];
                else if (col < 27) v = wo[((size_t)(col - 9) * 128 + c) * 9 + t];
                o[j] = f2bf(v);
            }
            uint4 u;
            u.x = (unsigned)o[0] | ((unsigned)o[1] << 16);
            u.y = (unsigned)o[2] | ((unsigned)o[3] << 16);
            u.z = (unsigned)o[4] | ((unsigned)o[5] << 16);
            u.w = (unsigned)o[6] | ((unsigned)o[7] << 16);
            *(uint4*)(Bf + (size_t)f * 8) = u;
        } else if (bx == 9) {
            // constant LUT
            if (tid < 64) {
                const float inv = g1[tid] * rsqrtf(v1[tid] + EPS);
                cst[tid] = w1[tid] * inv;                // dfA
                cst[64 + tid] = b1[tid] - m1[tid] * inv; // dfB
            } else if (tid < 64 + 27) {
                const int j = tid - 64;
                float g, bb, m, v;
                if (j < 9) { g = gw[j]; bb = bw[j]; m = mw[j]; v = vw[j]; }
                else       { g = go[j - 9]; bb = bo[j - 9]; m = mo[j - 9]; v = vo[j - 9]; }
                const float inv = g * rsqrtf(v + EPS);
                cst[128 + j] = inv;                 // eInv
                cst[155 + j] = bb - m * inv;        // eBias
            }
        }
        return;
    }
    const int y = blockIdx.x;            // 0..239
    const int b = blockIdx.y;
    const int lane = tid & 63;
    const int g = tid >> 6;              // 0..7
    const int c0 = g * 8;
    unsigned short* __restrict__ plane = (g < 4) ? lo : hi;
    const int slotg = g & 3;
    const float* __restrict__ fb = feature + (size_t)b * Cn * HW + (size_t)y * Wn;
    #pragma unroll
    for (int s = 0; s < 5; ++s) {
        const int x = s * 64 + lane;
        float v[8];
        #pragma unroll
        for (int j = 0; j < 8; ++j)
            v[j] = fb[(size_t)(c0 + j) * HW + x];
        uint4 u;
        u.x = cvtpk(v[0], v[1]); u.y = cvtpk(v[2], v[3]);
        u.z = cvtpk(v[4], v[5]); u.w = cvtpk(v[6], v[7]);
        const int slot = (slotg + ((x + 1) >> 1)) & 3;
        *(uint4*)(plane + (size_t)(b * HW + y * Wn + x) * 32 + slot * 8) = u;
    }
}

// ---- main: 16x16 tile, SINGLE staging buffer, 5 blocks/CU (TLP) ----------
__global__ __launch_bounds__(256, 5) void dkn_main(
    const unsigned short* __restrict__ Bf,
    const float* __restrict__ cst,
    const unsigned short* __restrict__ catLo,
    const unsigned short* __restrict__ catHi,
    const float* __restrict__ depth,
    float* __restrict__ out)
{
    __shared__ __align__(16) char lds[LDS_TOTAL];   // 31616 B

    const int tid = threadIdx.x;
    const int lane = tid & 63, wv = tid >> 6;       // 4 waves
    const int l15 = lane & 15, hi16 = lane >> 4;
    const int b = blockIdx.z;
    const int h0 = blockIdx.y * TM;
    const int w0 = blockIdx.x * TN;
    const float* __restrict__ dimg = depth + (size_t)b * HW;
    const float* __restrict__ dfA = cst;
    const float* __restrict__ dfB = cst + 64;
    const float* __restrict__ eInv = cst + 128;
    const float* __restrict__ eBias = cst + 155;

    char* S = lds;                                  // staging buffer (21504 B)
    float* winp = (float*)(lds + WINP_OFF);         // 31*31 f32, dedicated
    float* ldsT = (float*)lds;                      // 256*27 f32, post-GEMM alias

    const bool interior = (blockIdx.y >= 1) && (blockIdx.y <= 13)
                       && (blockIdx.x >= 1) && (blockIdx.x <= 18);

    // ---- depth sample window -> LDS immediately (read only in epilogue) ----
    #pragma unroll
    for (int s = 0; s < 4; ++s) {
        const int i = s * 256 + tid;              // over 961
        const int r = (i * 2115) >> 16;           // i/31, exact for i<=960
        const int c = i - r * 31;
        const int y = h0 + r - 7, x = w0 + c - 7;
        const bool inw = (i < WROWS * WCOLS);
        const bool oki = inw && ((unsigned)y < (unsigned)Hn) && ((unsigned)x < (unsigned)Wn);
        const float v = oki ? dimg[y * Wn + x] : 0.0f;
        if (inw) winp[i] = v;
    }

    // ---- df staging: thread owns granule g = tid&3 of px = s*64 + (tid>>2) --
    const int gdf = tid & 3;
    const int pxq = tid >> 2;
    auto stage_df = [&](int pt) {
        const int c0 = pt * 32 + gdf * 8;
        const float4 A0 = *(const float4*)(dfA + c0);
        const float4 A1 = *(const float4*)(dfA + c0 + 4);
        const float4 B0 = *(const float4*)(dfB + c0);
        const float4 B1 = *(const float4*)(dfB + c0 + 4);
        const float Ac[8] = {A0.x, A0.y, A0.z, A0.w, A1.x, A1.y, A1.z, A1.w};
        const float Bc[8] = {B0.x, B0.y, B0.z, B0.w, B1.x, B1.y, B1.z, B1.w};
        #pragma unroll
        for (int s = 0; s < 6; ++s) {
            const int px = s * 64 + pxq;
            if (px < NPXT) {
                const int r = (px * 57) >> 10;        // px/18, exact for px<324
                const int lc = px - r * 18;
                const int y = h0 + r - 1, x = w0 + lc - 1;
                const bool ok = ((unsigned)y < (unsigned)Hn) && ((unsigned)x < (unsigned)Wn);
                const float d = ok ? dimg[y * Wn + x] : 0.0f;
                float v[8];
                #pragma unroll
                for (int j = 0; j < 8; ++j) {
                    float u = fmaf(Ac[j], d, Bc[j]);
                    u = fmaxf(u, SLOPE * u);
                    v[j] = ok ? u : 0.0f;
                }
                uint4 u4;
                u4.x = cvtpk(v[0], v[1]); u4.y = cvtpk(v[2], v[3]);
                u4.z = cvtpk(v[4], v[5]); u4.w = cvtpk(v[6], v[7]);
                const int slot = (gdf + (lc >> 1)) & 3;
                *(uint4*)(S + px * 64 + slot * 16) = u4;
            }
        }
    };

    // ---- feature staging: async DMA from pre-swizzled plane ----
    auto issue_gll = [&](const unsigned short* __restrict__ plane) {
        #pragma unroll
        for (int s = 0; s < 6; ++s) {
            const int base = s * 256 + wv * 64;    // wave-uniform
            if (base < NGR) {
                int i = base + lane;
                i = min(i, NGR - 1);               // tail lanes duplicate (into pad)
                const int px = i >> 2, slot = i & 3;
                const int r = (px * 57) >> 10;
                const int lc = px - r * 18;
                const int y = min(max(h0 + r - 1, 0), Hn - 1);
                const int x = min(max(w0 + lc - 1, 0), Wn - 1);
                const unsigned short* src =
                    plane + (size_t)(b * HW + y * Wn + x) * 32 + slot * 8;
                __builtin_amdgcn_global_load_lds(
                    (const __attribute__((address_space(1))) void*)src,
                    (__attribute__((address_space(3))) void*)(S + (size_t)base * 16),
                    16, 0, 0);
            }
        }
    };
    auto borderfix = [&]() {
        #pragma unroll
        for (int s = 0; s < 6; ++s) {
            const int i = s * 256 + tid;
            if (i < NGR) {
                const int px = i >> 2;
                const int r = (px * 57) >> 10;
                const int lc = px - r * 18;
                const int y = h0 + r - 1, x = w0 + lc - 1;
                if (((unsigned)y >= (unsigned)Hn) || ((unsigned)x >= (unsigned)Wn)) {
                    uint4 z = {0u, 0u, 0u, 0u};
                    *(uint4*)(S + (size_t)i * 16) = z;
                }
            }
        }
    };

    // ---- MFMA: wave owns out-rows 4wv..4wv+3; rolling A window ----
    f32x4 acc[4][2] = {};
    const int r0 = 4 * wv;

    auto mfma_phase = [&](int p) {
        const unsigned short* Bp = Bf + (size_t)p * 9216;
        auto lda = [&](int row, int dx) -> bf16x8 {
            const int col = l15 + dx;                       // 0..17
            const int slot = (hi16 + (col >> 1)) & 3;
            return *(const bf16x8*)(S + (row * HC + col) * 64 + slot * 16);
        };
        auto ldb = [&](int idx) -> bf16x8 {                 // idx = t*2+n
            return *(const bf16x8*)(Bp + ((size_t)idx * 64 + lane) * 8);
        };
        auto do_dy = [&](const bf16x8* A0, const bf16x8* A1,
                         const bf16x8* A2, const bf16x8* A3, const bf16x8* bb) {
            #pragma unroll
            for (int dx = 0; dx < 3; ++dx) {
                acc[0][0] = __builtin_amdgcn_mfma_f32_16x16x32_bf16(A0[dx], bb[dx*2+0], acc[0][0], 0, 0, 0);
                acc[0][1] = __builtin_amdgcn_mfma_f32_16x16x32_bf16(A0[dx], bb[dx*2+1], acc[0][1], 0, 0, 0);
                acc[1][0] = __builtin_amdgcn_mfma_f32_16x16x32_bf16(A1[dx], bb[dx*2+0], acc[1][0], 0, 0, 0);
                acc[1][1] = __builtin_amdgcn_mfma_f32_16x16x32_bf16(A1[dx], bb[dx*2+1], acc[1][1], 0, 0, 0);
                acc[2][0] = __builtin_amdgcn_mfma_f32_16x16x32_bf16(A2[dx], bb[dx*2+0], acc[2][0], 0, 0, 0);
                acc[2][1] = __builtin_amdgcn_mfma_f32_16x16x32_bf16(A2[dx], bb[dx*2+1], acc[2][1], 0, 0, 0);
                acc[3][0] = __builtin_amdgcn_mfma_f32_16x16x32_bf16(A3[dx], bb[dx*2+0], acc[3][0], 0, 0, 0);
                acc[3][1] = __builtin_amdgcn_mfma_f32_16x16x32_bf16(A3[dx], bb[dx*2+1], acc[3][1], 0, 0, 0);
            }
        };
        bf16x8 a0[3], a1[3], a2[3], a3[3], a4[3], a5[3];
        bf16x8 b0[6], b1[6], b2[6];
        #pragma unroll
        for (int dx = 0; dx < 3; ++dx) {
            a0[dx] = lda(r0 + 0, dx); a1[dx] = lda(r0 + 1, dx);
            a2[dx] = lda(r0 + 2, dx); a3[dx] = lda(r0 + 3, dx);
        }
        #pragma unroll
        for (int i = 0; i < 6; ++i) b0[i] = ldb(i);
        #pragma unroll
        for (int dx = 0; dx < 3; ++dx) a4[dx] = lda(r0 + 4, dx);
        #pragma unroll
        for (int i = 0; i < 6; ++i) b1[i] = ldb(6 + i);
        do_dy(a0, a1, a2, a3, b0);
        #pragma unroll
        for (int dx = 0; dx < 3; ++dx) a5[dx] = lda(r0 + 5, dx);
        #pragma unroll
        for (int i = 0; i < 6; ++i) b2[i] = ldb(12 + i);
        do_dy(a1, a2, a3, a4, b1);
        do_dy(a2, a3, a4, a5, b2);
    };

    // ---- 4 phases, single buffer, barrier-separated (TLP hides latency) ----
    stage_df(0);
    __syncthreads();
    mfma_phase(0);
    __syncthreads();

    stage_df(1);
    __syncthreads();
    mfma_phase(1);
    __syncthreads();

    issue_gll(catLo);
    asm volatile("s_waitcnt vmcnt(0)" ::: "memory");
    if (!interior) borderfix();
    __syncthreads();
    mfma_phase(2);
    __syncthreads();

    issue_gll(catHi);
    asm volatile("s_waitcnt vmcnt(0)" ::: "memory");
    if (!interior) borderfix();
    __syncthreads();
    mfma_phase(3);
    __syncthreads();

    // ---- transpose acc -> ldsT [256 px][27 f32] (stride 27: conflict-free) --
    #pragma unroll
    for (int m = 0; m < 4; ++m) {
        const int oy = 4 * wv + m;
        #pragma unroll
        for (int n = 0; n < 2; ++n) {
            if (n == 0 || l15 < 11) {             // only channels 0..26
                #pragma unroll
                for (int r = 0; r < 4; ++r) {
                    const int ox = hi16 * 4 + r;
                    ldsT[(oy * TN + ox) * 27 + n * 16 + l15] = acc[m][n][r];
                }
            }
        }
    }
    __syncthreads();

    // ---- per-pixel epilogue ----
    {
        const int oyl = tid >> 4, oxl = tid & 15;
        const int h = h0 + oyl, w = w0 + oxl;
        const float* row = ldsT + (size_t)tid * 27;

        float wgt[9];
        float wsum = 0.0f;
        #pragma unroll
        for (int j = 0; j < 9; ++j) {
            const float x = fmaf(row[j], eInv[j], eBias[j]);
            const float e = fastexp(x);                 // e^x
            const float s = e * fastrcp(1.0f + e);      // sigmoid
            wgt[j] = s;
            wsum += s;
        }
        const float wm = wsum * (1.0f / 9.0f);
        #pragma unroll
        for (int j = 0; j < 9; ++j) wgt[j] -= wm;

        float offv[18];
        #pragma unroll
        for (int j = 0; j < 18; ++j)
            offv[j] = fmaf(row[9 + j], eInv[9 + j], eBias[9 + j]);

        auto sampleW = [&](float xf, float yf) -> float {
            const bool vld = (xf >= 0.0f) & (xf <= 14.0f) & (yf >= 0.0f) & (yf <= 14.0f);
            const int xi = min(max((int)xf, 0), 14);
            const int yi = min(max((int)yf, 0), 14);
            const float v = winp[(oyl + yi) * WCOLS + (oxl + xi)];
            return vld ? v : 0.0f;
        };

        float res = 0.0f;
        #pragma unroll
        for (int i = 0; i < 3; ++i) {
            #pragma unroll
            for (int j = 0; j < 3; ++j) {
                const int t = i * 3 + j;
                const float ox = offv[2 * t + 0];
                const float oy = offv[2 * t + 1];
                const float ix = (7.0f + (float)i + ox) * (14.0f / 15.0f);
                const float iy = (7.0f + (float)j + oy) * (14.0f / 15.0f);
                const float x0 = floorf(ix), y0 = floorf(iy);
                const float wx1 = ix - x0, wy1 = iy - y0;
                const float wx0 = 1.0f - wx1, wy0 = 1.0f - wy1;
                const float s =
                      sampleW(x0,        y0       ) * wx0 * wy0
                    + sampleW(x0 + 1.0f, y0       ) * wx1 * wy0
                    + sampleW(x0,        y0 + 1.0f) * wx0 * wy1
                    + sampleW(x0 + 1.0f, y0 + 1.0f) * wx1 * wy1;
                res = fmaf(s, wgt[t], res);
            }
        }
        out[((size_t)b * Hn + h) * Wn + w] = res + winp[(oyl + 7) * WCOLS + (oxl + 7)];
    }
}

// ---------------- round-1 fallback (fp32, fused, proven) ----------------
__global__ __launch_bounds__(256) void dkn_fused_f32(
    const float* __restrict__ depth, const float* __restrict__ feature,
    const float* __restrict__ w1, const float* __restrict__ g1,
    const float* __restrict__ b1, const float* __restrict__ m1,
    const float* __restrict__ v1, const float* __restrict__ ww,
    const float* __restrict__ gw, const float* __restrict__ bw,
    const float* __restrict__ mw, const float* __restrict__ vw,
    const float* __restrict__ wo, const float* __restrict__ go,
    const float* __restrict__ bo, const float* __restrict__ mo,
    const float* __restrict__ vo, float* __restrict__ out)
{
    const int n = blockIdx.x * blockDim.x + threadIdx.x;
    if (n >= Npix) return;
    const int w = n % Wn;
    const int h = (n / Wn) % Hn;
    const int b = n / (Wn * Hn);
    const float* __restrict__ dimg = depth + (size_t)b * HW;
    const float* __restrict__ fimg = feature + (size_t)b * Cn * HW;
    float d9[9], msk[9]; int off9[9];
    #pragma unroll
    for (int ky = 0; ky < 3; ++ky)
        #pragma unroll
        for (int kx = 0; kx < 3; ++kx) {
            const int t = ky * 3 + kx;
            const int y = h + ky - 1, x = w + kx - 1;
            const bool ok = ((unsigned)y < (unsigned)Hn) && ((unsigned)x < (unsigned)Wn);
            off9[t] = min(max(y, 0), Hn - 1) * Wn + min(max(x, 0), Wn - 1);
            d9[t] = dimg[off9[t]];
            msk[t] = ok ? 1.0f : 0.0f;
        }
    float accW[9], accO[18];
    #pragma unroll
    for (int o = 0; o < 9; ++o) accW[o] = 0.0f;
    #pragma unroll
    for (int o = 0; o < 18; ++o) accO[o] = 0.0f;
    for (int c = 0; c < Cn; ++c) {
        const float inv = g1[c] * rsqrtf(v1[c] + EPS);
        const float A = w1[c] * inv, Bc = b1[c] - m1[c] * inv;
        float v9[9];
        #pragma unroll
        for (int t = 0; t < 9; ++t) {
            const float x = fmaf(A, d9[t], Bc);
            v9[t] = msk[t] * fmaxf(x, SLOPE * x);
        }
        const float* wwc = ww + c * 9;
        const float* woc = wo + c * 9;
        #pragma unroll
        for (int o = 0; o < 9; ++o)
            #pragma unroll
            for (int t = 0; t < 9; ++t) accW[o] = fmaf(wwc[o * 1152 + t], v9[t], accW[o]);
        #pragma unroll
        for (int o = 0; o < 18; ++o)
            #pragma unroll
            for (int t = 0; t < 9; ++t) accO[o] = fmaf(woc[o * 1152 + t], v9[t], accO[o]);
    }
    for (int c = 0; c < Cn; ++c) {
        const float* fc = fimg + (size_t)c * HW;
        float v9[9];
        #pragma unroll
        for (int t = 0; t < 9; ++t) v9[t] = msk[t] * fc[off9[t]];
        const float* wwc = ww + (64 + c) * 9;
        const float* woc = wo + (64 + c) * 9;
        #pragma unroll
        for (int o = 0; o < 9; ++o)
            #pragma unroll
            for (int t = 0; t < 9; ++t) accW[o] = fmaf(wwc[o * 1152 + t], v9[t], accW[o]);
        #pragma unroll
        for (int o = 0; o < 18; ++o)
            #pragma unroll
            for (int t = 0; t < 9; ++t) accO[o] = fmaf(woc[o * 1152 + t], v9[t], accO[o]);
    }
    float wgt[9];
    float wsum = 0.0f;
    #pragma unroll
    for (int j = 0; j < 9; ++j) {
        const float inv = gw[j] * rsqrtf(vw[j] + EPS);
        const float x = fmaf(accW[j], inv, bw[j] - mw[j] * inv);
        const float s = 1.0f / (1.0f + expf(-x));
        wgt[j] = s; wsum += s;
    }
    const float wm = wsum * (1.0f / 9.0f);
    #pragma unroll
    for (int j = 0; j < 9; ++j) wgt[j] -= wm;
    float offv[18];
    #pragma unroll
    for (int j = 0; j < 18; ++j) {
        const float inv = go[j] * rsqrtf(vo[j] + EPS);
        offv[j] = fmaf(accO[j], inv, bo[j] - mo[j] * inv);
    }
    auto sampleD = [&](float xf, float yf) -> float {
        const bool vld = (xf >= 0.0f) & (xf <= 14.0f) & (yf >= 0.0f) & (yf <= 14.0f);
        const float xc = fminf(fmaxf(xf, 0.0f), 14.0f);
        const float yc = fminf(fmaxf(yf, 0.0f), 14.0f);
        const int xi = (int)xc, yi = (int)yc;
        const int yy = h + yi - 7, xx = w + xi - 7;
        const bool okimg = ((unsigned)yy < (unsigned)Hn) && ((unsigned)xx < (unsigned)Wn);
        return (vld && okimg) ? dimg[yy * Wn + xx] : 0.0f;
    };
    float res = 0.0f;
    #pragma unroll
    for (int i = 0; i < 3; ++i)
        #pragma unroll
        for (int j = 0; j < 3; ++j) {
            const int t = i * 3 + j;
            const float ox = offv[2 * t + 0], oy = offv[2 * t + 1];
            const float ix = (7.0f + (float)i + ox) * (14.0f / 15.0f);
            const float iy = (7.0f + (float)j + oy) * (14.0f / 15.0f);
            const float x0 = floorf(ix), y0 = floorf(iy);
            const float wx1 = ix - x0, wy1 = iy - y0;
            const float s = sampleD(x0, y0) * (1.0f - wx1) * (1.0f - wy1)
                          + sampleD(x0 + 1.0f, y0) * wx1 * (1.0f - wy1)
                          + sampleD(x0, y0 + 1.0f) * (1.0f - wx1) * wy1
                          + sampleD(x0 + 1.0f, y0 + 1.0f) * wx1 * wy1;
            res = fmaf(s, wgt[t], res);
        }
    out[n] = res + dimg[h * Wn + w];
}

extern "C" void kernel_launch(void* const* d_in, const int* in_sizes, int n_in,
                              void* d_out, int out_size, void* d_ws, size_t ws_size,
                              hipStream_t stream) {
    (void)in_sizes; (void)n_in; (void)out_size;
    const float* depth   = (const float*)d_in[0];
    const float* feature = (const float*)d_in[1];
    const float* w1 = (const float*)d_in[2];
    const float* g1 = (const float*)d_in[3];
    const float* b1 = (const float*)d_in[4];
    const float* m1 = (const float*)d_in[5];
    const float* v1 = (const float*)d_in[6];
    const float* ww = (const float*)d_in[7];
    const float* gw = (const float*)d_in[8];
    const float* bw = (const float*)d_in[9];
    const float* mw = (const float*)d_in[10];
    const float* vw = (const float*)d_in[11];
    const float* wo = (const float*)d_in[12];
    const float* go = (const float*)d_in[13];
    const float* bo = (const float*)d_in[14];
    const float* mo = (const float*)d_in[15];
    const float* vo = (const float*)d_in[16];
    float* out = (float*)d_out;

    if (ws_size >= WS_NEED) {
        unsigned short* Bmat  = (unsigned short*)d_ws;
        float* cst = (float*)((char*)d_ws + BMAT_BYTES);
        unsigned short* catLo = (unsigned short*)((char*)d_ws + LO_OFF);
        unsigned short* catHi = (unsigned short*)((char*)d_ws + HI_OFF);
        hipLaunchKernelGGL(prep_FB, dim3(Hn, Bn + 1), dim3(512), 0, stream,
                           feature, ww, wo, w1, g1, b1, m1, v1,
                           gw, bw, mw, vw, go, bo, mo, vo,
                           catLo, catHi, Bmat, cst);
        hipLaunchKernelGGL(dkn_main, dim3(Wn / TN, Hn / TM, Bn), dim3(256), 0, stream,
                           Bmat, cst, catLo, catHi, depth, out);
    } else {
        hipLaunchKernelGGL(dkn_fused_f32, dim3((Npix + 255) / 256), dim3(256), 0, stream,
                           depth, feature, w1, g1, b1, m1, v1,
                           ww, gw, bw, mw, vw, wo, go, bo, mo, vo, out);
    }
}

// Round 10
// 62.047 us; speedup vs baseline: 1.2347x; 1.1731x over previous
//
#include <hip/hip_runtime.h>
#include <hip/hip_bf16.h>
#include <math.h>

namespace {
constexpr int Bn = 4, Cn = 64, Hn = 240, Wn = 320;
constexpr int HW = Hn * Wn;
constexpr int Npix = Bn * HW;
constexpr float EPS = 1e-5f;
constexpr float SLOPE = 0.2f;
constexpr int TM = 16, TN = 16;              // output tile
constexpr int HR = TM + 2, HC = TN + 2;      // halo 18 x 18
constexpr int NPXT = HR * HC;                // 324 pixels
constexpr int NGR = NPXT * 4;                // 1296 granules (16B) per phase
constexpr int PHB = 1344 * 16;               // 21504 B (pad for gll tail)
constexpr int WROWS = 31, WCOLS = 31;        // depth sample window
constexpr size_t BMAT_BYTES = 4 * 9 * 2 * 64 * 8 * 2;    // 73728 (frag-major)
constexpr size_t CONST_BYTES = 1024;                      // dfA/dfB/eInv/eBias
constexpr size_t PLANE_BYTES = (size_t)Bn * HW * 32 * 2; // 19.66 MB per plane
constexpr size_t LO_OFF = BMAT_BYTES + CONST_BYTES;
constexpr size_t HI_OFF = LO_OFF + PLANE_BYTES;
constexpr size_t WS_NEED = HI_OFF + PLANE_BYTES;
}

typedef __attribute__((ext_vector_type(8))) short bf16x8;
typedef __attribute__((ext_vector_type(4))) float f32x4;

__device__ inline unsigned cvtpk(float lo, float hi) {
    unsigned r;
    asm("v_cvt_pk_bf16_f32 %0, %1, %2" : "=v"(r) : "v"(lo), "v"(hi));
    return r;
}

__device__ inline float fastexp(float x) {
    float e;
    asm("v_exp_f32 %0, %1" : "=v"(e) : "v"(x * 1.44269504f));
    return e;
}

__device__ inline float fastrcp(float x) {
    float r;
    asm("v_rcp_f32 %0, %1" : "=v"(r) : "v"(x));
    return r;
}

__device__ inline unsigned short f2bf(float f) {
    unsigned u = __builtin_bit_cast(unsigned, f);
    return (unsigned short)((u + 0x7fffu + ((u >> 16) & 1u)) >> 16);
}

// ---- merged pre-pass: feature f32 -> bf16 pixel-major planes (pre-swizzled)
//      + weight frags Bf[p][t][n][lane64][8] + constant LUT ----
__global__ __launch_bounds__(512) void prep_FB(
    const float* __restrict__ feature,
    const float* __restrict__ ww, const float* __restrict__ wo,
    const float* __restrict__ w1, const float* __restrict__ g1,
    const float* __restrict__ b1, const float* __restrict__ m1,
    const float* __restrict__ v1,
    const float* __restrict__ gw, const float* __restrict__ bw,
    const float* __restrict__ mw, const float* __restrict__ vw,
    const float* __restrict__ go, const float* __restrict__ bo,
    const float* __restrict__ mo, const float* __restrict__ vo,
    unsigned short* __restrict__ lo, unsigned short* __restrict__ hi,
    unsigned short* __restrict__ Bf, float* __restrict__ cst)
{
    const int tid = threadIdx.x;
    if (blockIdx.y == Bn) {
        const int bx = blockIdx.x;
        if (bx < 9) {
            // weight fragments: f over 4608 = 9 blocks x 512
            const int f = bx * 512 + tid;
            const int lane = f & 63, rest = f >> 6;
            const int n = rest & 1, tp = rest >> 1;   // tp = p*9 + t
            const int t = tp % 9, p = tp / 9;
            const int col = n * 16 + (lane & 15);
            const int hh = lane >> 4;
            unsigned short o[8];
            #pragma unroll
            for (int j = 0; j < 8; ++j) {
                const int c = p * 32 + hh * 8 + j;
                float v = 0.0f;
                if (col < 9)       v = ww[((size_t)col * 128 + c) * 9 + t];
                else if (col < 27) v = wo[((size_t)(col - 9) * 128 + c) * 9 + t];
                o[j] = f2bf(v);
            }
            uint4 u;
            u.x = (unsigned)o[0] | ((unsigned)o[1] << 16);
            u.y = (unsigned)o[2] | ((unsigned)o[3] << 16);
            u.z = (unsigned)o[4] | ((unsigned)o[5] << 16);
            u.w = (unsigned)o[6] | ((unsigned)o[7] << 16);
            *(uint4*)(Bf + (size_t)f * 8) = u;
        } else if (bx == 9) {
            // constant LUT
            if (tid < 64) {
                const float inv = g1[tid] * rsqrtf(v1[tid] + EPS);
                cst[tid] = w1[tid] * inv;                // dfA
                cst[64 + tid] = b1[tid] - m1[tid] * inv; // dfB
            } else if (tid < 64 + 27) {
                const int j = tid - 64;
                float g, bb, m, v;
                if (j < 9) { g = gw[j]; bb = bw[j]; m = mw[j]; v = vw[j]; }
                else       { g = go[j - 9]; bb = bo[j - 9]; m = mo[j - 9]; v = vo[j - 9]; }
                const float inv = g * rsqrtf(v + EPS);
                cst[128 + j] = inv;                 // eInv
                cst[155 + j] = bb - m * inv;        // eBias
            }
        }
        return;
    }
    const int y = blockIdx.x;            // 0..239
    const int b = blockIdx.y;
    const int lane = tid & 63;
    const int g = tid >> 6;              // 0..7
    const int c0 = g * 8;
    unsigned short* __restrict__ plane = (g < 4) ? lo : hi;
    const int slotg = g & 3;
    const float* __restrict__ fb = feature + (size_t)b * Cn * HW + (size_t)y * Wn;
    #pragma unroll
    for (int s = 0; s < 5; ++s) {
        const int x = s * 64 + lane;
        float v[8];
        #pragma unroll
        for (int j = 0; j < 8; ++j)
            v[j] = fb[(size_t)(c0 + j) * HW + x];
        uint4 u;
        u.x = cvtpk(v[0], v[1]); u.y = cvtpk(v[2], v[3]);
        u.z = cvtpk(v[4], v[5]); u.w = cvtpk(v[6], v[7]);
        const int slot = (slotg + ((x + 1) >> 1)) & 3;
        *(uint4*)(plane + (size_t)(b * HW + y * Wn + x) * 32 + slot * 8) = u;
    }
}

// ---- main (R7-proven): 16x16 tile, 4 waves, dbuf, 3 blocks/CU ----------
__global__ __launch_bounds__(256, 3) void dkn_main(
    const unsigned short* __restrict__ Bf,
    const float* __restrict__ cst,
    const unsigned short* __restrict__ catLo,
    const unsigned short* __restrict__ catHi,
    const float* __restrict__ depth,
    float* __restrict__ out)
{
    __shared__ __align__(16) char lds[2 * PHB];   // 43008 B -> 3 blocks/CU

    const int tid = threadIdx.x;
    const int lane = tid & 63, wv = tid >> 6;     // 4 waves
    const int b = blockIdx.z;
    const int h0 = blockIdx.y * TM;
    const int w0 = blockIdx.x * TN;
    const float* __restrict__ dimg = depth + (size_t)b * HW;
    const float* __restrict__ dfA = cst;
    const float* __restrict__ dfB = cst + 64;
    const float* __restrict__ eInv = cst + 128;
    const float* __restrict__ eBias = cst + 155;

    char* buf0 = lds;
    char* buf1 = lds + PHB;
    float* winp = (float*)lds;                    // 31*31*4 B (phase-3 time)
    float* ldsT = (float*)(lds + 3968);           // 256*33*4 B (post-GEMM)

    const bool interior = (blockIdx.y >= 1) && (blockIdx.y <= 13)
                       && (blockIdx.x >= 1) && (blockIdx.x <= 18);

    // ---- df staging: thread owns granule g = tid&3 of px = s*64 + (tid>>2) --
    const int gdf = tid & 3;
    const int pxq = tid >> 2;
    auto stage_df = [&](int pt, char* buf) {
        const int c0 = pt * 32 + gdf * 8;
        const float4 A0 = *(const float4*)(dfA + c0);
        const float4 A1 = *(const float4*)(dfA + c0 + 4);
        const float4 B0 = *(const float4*)(dfB + c0);
        const float4 B1 = *(const float4*)(dfB + c0 + 4);
        const float Ac[8] = {A0.x, A0.y, A0.z, A0.w, A1.x, A1.y, A1.z, A1.w};
        const float Bc[8] = {B0.x, B0.y, B0.z, B0.w, B1.x, B1.y, B1.z, B1.w};
        #pragma unroll
        for (int s = 0; s < 6; ++s) {
            const int px = s * 64 + pxq;
            if (px < NPXT) {
                const int r = (px * 57) >> 10;        // px/18, exact for px<324
                const int lc = px - r * 18;
                const int y = h0 + r - 1, x = w0 + lc - 1;
                const bool ok = ((unsigned)y < (unsigned)Hn) && ((unsigned)x < (unsigned)Wn);
                const float d = ok ? dimg[y * Wn + x] : 0.0f;
                float v[8];
                #pragma unroll
                for (int j = 0; j < 8; ++j) {
                    float u = fmaf(Ac[j], d, Bc[j]);
                    u = fmaxf(u, SLOPE * u);
                    v[j] = ok ? u : 0.0f;
                }
                uint4 u4;
                u4.x = cvtpk(v[0], v[1]); u4.y = cvtpk(v[2], v[3]);
                u4.z = cvtpk(v[4], v[5]); u4.w = cvtpk(v[6], v[7]);
                const int slot = (gdf + (lc >> 1)) & 3;
                *(uint4*)(buf + px * 64 + slot * 16) = u4;
            }
        }
    };

    // ---- feature staging: async DMA from pre-swizzled plane ----
    auto issue_gll = [&](const unsigned short* __restrict__ plane, char* buf) {
        #pragma unroll
        for (int s = 0; s < 6; ++s) {
            const int base = s * 256 + wv * 64;    // wave-uniform
            if (base < NGR) {
                int i = base + lane;
                i = min(i, NGR - 1);               // tail lanes duplicate (into pad)
                const int px = i >> 2, slot = i & 3;
                const int r = (px * 57) >> 10;
                const int lc = px - r * 18;
                const int y = min(max(h0 + r - 1, 0), Hn - 1);
                const int x = min(max(w0 + lc - 1, 0), Wn - 1);
                const unsigned short* src =
                    plane + (size_t)(b * HW + y * Wn + x) * 32 + slot * 8;
                __builtin_amdgcn_global_load_lds(
                    (const __attribute__((address_space(1))) void*)src,
                    (__attribute__((address_space(3))) void*)(buf + (size_t)base * 16),
                    16, 0, 0);
            }
        }
    };
    auto borderfix = [&](char* buf) {
        #pragma unroll
        for (int s = 0; s < 6; ++s) {
            const int i = s * 256 + tid;
            if (i < NGR) {
                const int px = i >> 2;
                const int r = (px * 57) >> 10;
                const int lc = px - r * 18;
                const int y = h0 + r - 1, x = w0 + lc - 1;
                if (((unsigned)y >= (unsigned)Hn) || ((unsigned)x >= (unsigned)Wn)) {
                    uint4 z = {0u, 0u, 0u, 0u};
                    *(uint4*)(buf + (size_t)i * 16) = z;
                }
            }
        }
    };

    // ---- MFMA: wave owns out-rows 4wv..4wv+3; rolling A window ----
    const int l15 = lane & 15, hi16 = lane >> 4;
    f32x4 acc[4][2] = {};

    auto mfma_phase = [&](int p, const char* buf) {
        const unsigned short* Bp = Bf + (size_t)p * 9216;
        auto lda = [&](int row, int dx) -> bf16x8 {
            const int col = l15 + dx;                       // 0..17
            const int slot = (hi16 + (col >> 1)) & 3;
            return *(const bf16x8*)(buf + (row * HC + col) * 64 + slot * 16);
        };
        auto ldb = [&](int idx) -> bf16x8 {                 // idx = t*2+n
            return *(const bf16x8*)(Bp + ((size_t)idx * 64 + lane) * 8);
        };
        auto do_dy = [&](const bf16x8* A0, const bf16x8* A1,
                         const bf16x8* A2, const bf16x8* A3, const bf16x8* bb) {
            #pragma unroll
            for (int dx = 0; dx < 3; ++dx) {
                acc[0][0] = __builtin_amdgcn_mfma_f32_16x16x32_bf16(A0[dx], bb[dx*2+0], acc[0][0], 0, 0, 0);
                acc[0][1] = __builtin_amdgcn_mfma_f32_16x16x32_bf16(A0[dx], bb[dx*2+1], acc[0][1], 0, 0, 0);
                acc[1][0] = __builtin_amdgcn_mfma_f32_16x16x32_bf16(A1[dx], bb[dx*2+0], acc[1][0], 0, 0, 0);
                acc[1][1] = __builtin_amdgcn_mfma_f32_16x16x32_bf16(A1[dx], bb[dx*2+1], acc[1][1], 0, 0, 0);
                acc[2][0] = __builtin_amdgcn_mfma_f32_16x16x32_bf16(A2[dx], bb[dx*2+0], acc[2][0], 0, 0, 0);
                acc[2][1] = __builtin_amdgcn_mfma_f32_16x16x32_bf16(A2[dx], bb[dx*2+1], acc[2][1], 0, 0, 0);
                acc[3][0] = __builtin_amdgcn_mfma_f32_16x16x32_bf16(A3[dx], bb[dx*2+0], acc[3][0], 0, 0, 0);
                acc[3][1] = __builtin_amdgcn_mfma_f32_16x16x32_bf16(A3[dx], bb[dx*2+1], acc[3][1], 0, 0, 0);
            }
        };
        const int r0 = 4 * wv;
        bf16x8 a0[3], a1[3], a2[3], a3[3], a4[3], a5[3];
        bf16x8 b0[6], b1[6], b2[6];
        #pragma unroll
        for (int dx = 0; dx < 3; ++dx) {
            a0[dx] = lda(r0 + 0, dx); a1[dx] = lda(r0 + 1, dx);
            a2[dx] = lda(r0 + 2, dx); a3[dx] = lda(r0 + 3, dx);
        }
        #pragma unroll
        for (int i = 0; i < 6; ++i) b0[i] = ldb(i);
        #pragma unroll
        for (int dx = 0; dx < 3; ++dx) a4[dx] = lda(r0 + 4, dx);
        #pragma unroll
        for (int i = 0; i < 6; ++i) b1[i] = ldb(6 + i);
        do_dy(a0, a1, a2, a3, b0);
        #pragma unroll
        for (int dx = 0; dx < 3; ++dx) a5[dx] = lda(r0 + 5, dx);
        #pragma unroll
        for (int i = 0; i < 6; ++i) b2[i] = ldb(12 + i);
        do_dy(a1, a2, a3, a4, b1);
        do_dy(a2, a3, a4, a5, b2);
    };

    stage_df(0, buf0);
    __syncthreads();

    mfma_phase(0, buf0);
    stage_df(1, buf1);
    __syncthreads();

    issue_gll(catLo, buf0);          // overlaps phase-1 MFMA
    mfma_phase(1, buf1);
    asm volatile("s_waitcnt vmcnt(0)" ::: "memory");
    if (!interior) borderfix(buf0);
    __syncthreads();

    issue_gll(catHi, buf1);          // overlaps phase-2 MFMA
    mfma_phase(2, buf0);
    asm volatile("s_waitcnt vmcnt(0)" ::: "memory");
    if (!interior) borderfix(buf1);
    __syncthreads();

    // phase-3 MFMA; gather the depth sample window meanwhile (buf0 free)
    float wvv[4];
    int widx[4];
    bool wok[4];
    #pragma unroll
    for (int s = 0; s < 4; ++s) {
        const int i = s * 256 + tid;              // over 961
        const int r = (i * 2115) >> 16;           // i/31, exact for i<=960
        const int c = i - r * 31;
        const int y = h0 + r - 7, x = w0 + c - 7;
        const bool inw = (i < WROWS * WCOLS);
        const bool oki = inw && ((unsigned)y < (unsigned)Hn) && ((unsigned)x < (unsigned)Wn);
        widx[s] = i;
        wok[s] = inw;
        wvv[s] = oki ? dimg[y * Wn + x] : 0.0f;
    }
    mfma_phase(3, buf1);
    #pragma unroll
    for (int s = 0; s < 4; ++s)
        if (wok[s]) winp[widx[s]] = wvv[s];
    __syncthreads();

    // ---- transpose acc -> ldsT [256 px][33 f32] ----
    #pragma unroll
    for (int m = 0; m < 4; ++m) {
        const int oy = 4 * wv + m;
        #pragma unroll
        for (int n = 0; n < 2; ++n) {
            #pragma unroll
            for (int r = 0; r < 4; ++r) {
                const int ox = hi16 * 4 + r;
                ldsT[(oy * TN + ox) * 33 + n * 16 + l15] = acc[m][n][r];
            }
        }
    }
    __syncthreads();

    // ---- per-pixel epilogue ----
    {
        const int oyl = tid >> 4, oxl = tid & 15;
        const int h = h0 + oyl, w = w0 + oxl;
        const float* row = ldsT + (size_t)tid * 33;

        float wgt[9];
        float wsum = 0.0f;
        #pragma unroll
        for (int j = 0; j < 9; ++j) {
            const float x = fmaf(row[j], eInv[j], eBias[j]);
            const float e = fastexp(x);                 // e^x
            const float s = e * fastrcp(1.0f + e);      // sigmoid
            wgt[j] = s;
            wsum += s;
        }
        const float wm = wsum * (1.0f / 9.0f);
        #pragma unroll
        for (int j = 0; j < 9; ++j) wgt[j] -= wm;

        float offv[18];
        #pragma unroll
        for (int j = 0; j < 18; ++j)
            offv[j] = fmaf(row[9 + j], eInv[9 + j], eBias[9 + j]);

        auto sampleW = [&](float xf, float yf) -> float {
            const bool vld = (xf >= 0.0f) & (xf <= 14.0f) & (yf >= 0.0f) & (yf <= 14.0f);
            const int xi = min(max((int)xf, 0), 14);
            const int yi = min(max((int)yf, 0), 14);
            const float v = winp[(oyl + yi) * WCOLS + (oxl + xi)];
            return vld ? v : 0.0f;
        };

        float res = 0.0f;
        #pragma unroll
        for (int i = 0; i < 3; ++i) {
            #pragma unroll
            for (int j = 0; j < 3; ++j) {
                const int t = i * 3 + j;
                const float ox = offv[2 * t + 0];
                const float oy = offv[2 * t + 1];
                const float ix = (7.0f + (float)i + ox) * (14.0f / 15.0f);
                const float iy = (7.0f + (float)j + oy) * (14.0f / 15.0f);
                const float x0 = floorf(ix), y0 = floorf(iy);
                const float wx1 = ix - x0, wy1 = iy - y0;
                const float wx0 = 1.0f - wx1, wy0 = 1.0f - wy1;
                const float s =
                      sampleW(x0,        y0       ) * wx0 * wy0
                    + sampleW(x0 + 1.0f, y0       ) * wx1 * wy0
                    + sampleW(x0,        y0 + 1.0f) * wx0 * wy1
                    + sampleW(x0 + 1.0f, y0 + 1.0f) * wx1 * wy1;
                res = fmaf(s, wgt[t], res);
            }
        }
        out[((size_t)b * Hn + h) * Wn + w] = res + winp[(oyl + 7) * WCOLS + (oxl + 7)];
    }
}

// ---------------- round-1 fallback (fp32, fused, proven) ----------------
__global__ __launch_bounds__(256) void dkn_fused_f32(
    const float* __restrict__ depth, const float* __restrict__ feature,
    const float* __restrict__ w1, const float* __restrict__ g1,
    const float* __restrict__ b1, const float* __restrict__ m1,
    const float* __restrict__ v1, const float* __restrict__ ww,
    const float* __restrict__ gw, const float* __restrict__ bw,
    const float* __restrict__ mw, const float* __restrict__ vw,
    const float* __restrict__ wo, const float* __restrict__ go,
    const float* __restrict__ bo, const float* __restrict__ mo,
    const float* __restrict__ vo, float* __restrict__ out)
{
    const int n = blockIdx.x * blockDim.x + threadIdx.x;
    if (n >= Npix) return;
    const int w = n % Wn;
    const int h = (n / Wn) % Hn;
    const int b = n / (Wn * Hn);
    const float* __restrict__ dimg = depth + (size_t)b * HW;
    const float* __restrict__ fimg = feature + (size_t)b * Cn * HW;
    float d9[9], msk[9]; int off9[9];
    #pragma unroll
    for (int ky = 0; ky < 3; ++ky)
        #pragma unroll
        for (int kx = 0; kx < 3; ++kx) {
            const int t = ky * 3 + kx;
            const int y = h + ky - 1, x = w + kx - 1;
            const bool ok = ((unsigned)y < (unsigned)Hn) && ((unsigned)x < (unsigned)Wn);
            off9[t] = min(max(y, 0), Hn - 1) * Wn + min(max(x, 0), Wn - 1);
            d9[t] = dimg[off9[t]];
            msk[t] = ok ? 1.0f : 0.0f;
        }
    float accW[9], accO[18];
    #pragma unroll
    for (int o = 0; o < 9; ++o) accW[o] = 0.0f;
    #pragma unroll
    for (int o = 0; o < 18; ++o) accO[o] = 0.0f;
    for (int c = 0; c < Cn; ++c) {
        const float inv = g1[c] * rsqrtf(v1[c] + EPS);
        const float A = w1[c] * inv, Bc = b1[c] - m1[c] * inv;
        float v9[9];
        #pragma unroll
        for (int t = 0; t < 9; ++t) {
            const float x = fmaf(A, d9[t], Bc);
            v9[t] = msk[t] * fmaxf(x, SLOPE * x);
        }
        const float* wwc = ww + c * 9;
        const float* woc = wo + c * 9;
        #pragma unroll
        for (int o = 0; o < 9; ++o)
            #pragma unroll
            for (int t = 0; t < 9; ++t) accW[o] = fmaf(wwc[o * 1152 + t], v9[t], accW[o]);
        #pragma unroll
        for (int o = 0; o < 18; ++o)
            #pragma unroll
            for (int t = 0; t < 9; ++t) accO[o] = fmaf(woc[o * 1152 + t], v9[t], accO[o]);
    }
    for (int c = 0; c < Cn; ++c) {
        const float* fc = fimg + (size_t)c * HW;
        float v9[9];
        #pragma unroll
        for (int t = 0; t < 9; ++t) v9[t] = msk[t] * fc[off9[t]];
        const float* wwc = ww + (64 + c) * 9;
        const float* woc = wo + (64 + c) * 9;
        #pragma unroll
        for (int o = 0; o < 9; ++o)
            #pragma unroll
            for (int t = 0; t < 9; ++t) accW[o] = fmaf(wwc[o * 1152 + t], v9[t], accW[o]);
        #pragma unroll
        for (int o = 0; o < 18; ++o)
            #pragma unroll
            for (int t = 0; t < 9; ++t) accO[o] = fmaf(woc[o * 1152 + t], v9[t], accO[o]);
    }
    float wgt[9];
    float wsum = 0.0f;
    #pragma unroll
    for (int j = 0; j < 9; ++j) {
        const float inv = gw[j] * rsqrtf(vw[j] + EPS);
        const float x = fmaf(accW[j], inv, bw[j] - mw[j] * inv);
        const float s = 1.0f / (1.0f + expf(-x));
        wgt[j] = s; wsum += s;
    }
    const float wm = wsum * (1.0f / 9.0f);
    #pragma unroll
    for (int j = 0; j < 9; ++j) wgt[j] -= wm;
    float offv[18];
    #pragma unroll
    for (int j = 0; j < 18; ++j) {
        const float inv = go[j] * rsqrtf(vo[j] + EPS);
        offv[j] = fmaf(accO[j], inv, bo[j] - mo[j] * inv);
    }
    auto sampleD = [&](float xf, float yf) -> float {
        const bool vld = (xf >= 0.0f) & (xf <= 14.0f) & (yf >= 0.0f) & (yf <= 14.0f);
        const float xc = fminf(fmaxf(xf, 0.0f), 14.0f);
        const float yc = fminf(fmaxf(yf, 0.0f), 14.0f);
        const int xi = (int)xc, yi = (int)yc;
        const int yy = h + yi - 7, xx = w + xi - 7;
        const bool okimg = ((unsigned)yy < (unsigned)Hn) && ((unsigned)xx < (unsigned)Wn);
        return (vld && okimg) ? dimg[yy * Wn + xx] : 0.0f;
    };
    float res = 0.0f;
    #pragma unroll
    for (int i = 0; i < 3; ++i)
        #pragma unroll
        for (int j = 0; j < 3; ++j) {
            const int t = i * 3 + j;
            const float ox = offv[2 * t + 0], oy = offv[2 * t + 1];
            const float ix = (7.0f + (float)i + ox) * (14.0f / 15.0f);
            const float iy = (7.0f + (float)j + oy) * (14.0f / 15.0f);
            const float x0 = floorf(ix), y0 = floorf(iy);
            const float wx1 = ix - x0, wy1 = iy - y0;
            const float s = sampleD(x0, y0) * (1.0f - wx1) * (1.0f - wy1)
                          + sampleD(x0 + 1.0f, y0) * wx1 * (1.0f - wy1)
                          + sampleD(x0, y0 + 1.0f) * (1.0f - wx1) * wy1
                          + sampleD(x0 + 1.0f, y0 + 1.0f) * wx1 * wy1;
            res = fmaf(s, wgt[t], res);
        }
    out[n] = res + dimg[h * Wn + w];
}

extern "C" void kernel_launch(void* const* d_in, const int* in_sizes, int n_in,
                              void* d_out, int out_size, void* d_ws, size_t ws_size,
                              hipStream_t stream) {
    (void)in_sizes; (void)n_in; (void)out_size;
    const float* depth   = (const float*)d_in[0];
    const float* feature = (const float*)d_in[1];
    const float* w1 = (const float*)d_in[2];
    const float* g1 = (const float*)d_in[3];
    const float* b1 = (const float*)d_in[4];
    const float* m1 = (const float*)d_in[5];
    const float* v1 = (const float*)d_in[6];
    const float* ww = (const float*)d_in[7];
    const float* gw = (const float*)d_in[8];
    const float* bw = (const float*)d_in[9];
    const float* mw = (const float*)d_in[10];
    const float* vw = (const float*)d_in[11];
    const float* wo = (const float*)d_in[12];
    const float* go = (const float*)d_in[13];
    const float* bo = (const float*)d_in[14];
    const float* mo = (const float*)d_in[15];
    const float* vo = (const float*)d_in[16];
    float* out = (float*)d_out;

    if (ws_size >= WS_NEED) {
        unsigned short* Bmat  = (unsigned short*)d_ws;
        float* cst = (float*)((char*)d_ws + BMAT_BYTES);
        unsigned short* catLo = (unsigned short*)((char*)d_ws + LO_OFF);
        unsigned short* catHi = (unsigned short*)((char*)d_ws + HI_OFF);
        hipLaunchKernelGGL(prep_FB, dim3(Hn, Bn + 1), dim3(512), 0, stream,
                           feature, ww, wo, w1, g1, b1, m1, v1,
                           gw, bw, mw, vw, go, bo, mo, vo,
                           catLo, catHi, Bmat, cst);
        hipLaunchKernelGGL(dkn_main, dim3(Wn / TN, Hn / TM, Bn), dim3(256), 0, stream,
                           Bmat, cst, catLo, catHi, depth, out);
    } else {
        hipLaunchKernelGGL(dkn_fused_f32, dim3((Npix + 255) / 256), dim3(256), 0, stream,
                           depth, feature, w1, g1, b1, m1, v1,
                           ww, gw, bw, mw, vw, wo, go, bo, mo, vo, out);
    }
}